// Round 6
// baseline (248.724 us; speedup 1.0000x reference)
//
#include <hip/hip_runtime.h>
#include <stdint.h>

// NeRF NewSampler: per-ray inverse-CDF fine sampling (JAX threefry-exact),
// merge with coarse samples via stable rank-scatter, expand to ray points.
//
// RNG hypothesis this round (variant F): partitionable counter mode per
// jax/_src/prng.py _threefry_random_bits_partitionable:
//   counts = iota(uint64, size); cipher((hi=counts>>32, lo=counts)) -> (y0,y1)
//   bit_width==32  ->  bits = y0 ^ y1         <-- the XOR fold, untested before
// Cipher core verified vs Random123 KAT + legacy scalar anchor 0.41845703125.
//
// Falsified: legacy split-halves (R1); (0,gi) keep-y1 (R2); (gi,0) keep-y1 (R3);
// (0,gi) keep-y0 (R4); pair-packed LE (R5).
//
// One wave (64 lanes) per ray. Block = 256 threads = 4 rays.

__device__ __forceinline__ uint32_t rotl32(uint32_t x, uint32_t d) {
  return (x << d) | (x >> (32u - d));
}

// JAX threefry2x32, key (0, 42). KAT-verified schedule. Returns y0 ^ y1.
__device__ __forceinline__ uint32_t threefry2x32_xor(uint32_t x0i, uint32_t x1i) {
  uint32_t x0 = x0i;
  uint32_t x1 = x1i;
  const uint32_t ks0 = 0u;
  const uint32_t ks1 = 42u;
  const uint32_t ks2 = 0x1BD11BDAu ^ 0u ^ 42u;  // 0x1BD11BF0
#define TF_ROUND(r) { x0 += x1; x1 = rotl32(x1, r); x1 ^= x0; }
  x0 += ks0; x1 += ks1;
  TF_ROUND(13) TF_ROUND(15) TF_ROUND(26) TF_ROUND(6)
  x0 += ks1; x1 += ks2 + 1u;
  TF_ROUND(17) TF_ROUND(29) TF_ROUND(16) TF_ROUND(24)
  x0 += ks2; x1 += ks0 + 2u;
  TF_ROUND(13) TF_ROUND(15) TF_ROUND(26) TF_ROUND(6)
  x0 += ks0; x1 += ks1 + 3u;
  TF_ROUND(17) TF_ROUND(29) TF_ROUND(16) TF_ROUND(24)
  x0 += ks1; x1 += ks2 + 4u;
  TF_ROUND(13) TF_ROUND(15) TF_ROUND(26) TF_ROUND(6)
  x0 += ks2; x1 += ks0 + 5u;
#undef TF_ROUND
  return x0 ^ x1;
}

__global__ __launch_bounds__(256) void newsampler_kernel(
    const float* __restrict__ rays_o,
    const float* __restrict__ rays_d,
    const float* __restrict__ s_vals,
    const float* __restrict__ weights,
    float* __restrict__ out,
    int nrays)
{
  __shared__ __align__(16) float ls_scan[4][64];  // cdf with +inf sentinels at 62,63
  __shared__ __align__(16) float ls_fine[4][64];
  __shared__ __align__(16) float ls_sv[4][64];
  __shared__ __align__(16) float ls_srt[4][128];

  const int lane = threadIdx.x & 63;
  const int wv   = threadIdx.x >> 6;
  int ray = blockIdx.x * 4 + wv;
  if (ray >= nrays) ray = nrays - 1;  // benign duplicate work (nrays % 4 == 0 anyway)

  // ---- load per-lane coarse depth + weight (coalesced) ----
  const float sv = s_vals[(size_t)ray * 64 + lane];
  const float wt = weights[(size_t)ray * 64 + lane];

  // ---- bins: mid[j] = 0.5*(s[j] + s[j+1]), valid lanes 0..62 ----
  const float sv_next = __shfl_down(sv, 1);
  const float bin = 0.5f * (sv + sv_next);

  // ---- pdf over weights[1..62] (+1e-6), cdf prefix ----
  const float wm = (lane >= 1 && lane <= 62) ? (wt + 1e-6f) : 0.0f;
  float tot = wm;
  #pragma unroll
  for (int s = 1; s < 64; s <<= 1) tot += __shfl_xor(tot, s);
  const float pdf = wm / tot;
  float cdf = pdf;  // inclusive prefix -> cdf_full[lane], lane 0 == 0.0
  #pragma unroll
  for (int s = 1; s < 64; s <<= 1) {
    float t = __shfl_up(cdf, s);
    if (lane >= s) cdf += t;
  }

  // stash cdf for the linear searchsorted scan; sentinel so above <= 62
  ls_scan[wv][lane] = (lane < 62) ? cdf : 3.0e38f;
  __syncthreads();

  // ---- u: variant F — bits = y0 ^ y1 of cipher((0, gi)) ----
  const uint32_t gi = (uint32_t)ray * 64u + (uint32_t)lane;
  const uint32_t bits = threefry2x32_xor(0u, gi);
  const float u = __uint_as_float((bits >> 9) | 0x3f800000u) - 1.0f;

  // ---- searchsorted(cdf[0:62], u, side='right') via broadcast float4 scan ----
  int above = 0;
  const float4* cs = (const float4*)ls_scan[wv];
  #pragma unroll
  for (int it = 0; it < 16; ++it) {
    float4 c = cs[it];
    above += (int)(c.x <= u) + (int)(c.y <= u) + (int)(c.z <= u) + (int)(c.w <= u);
  }
  const int below = above - 1;  // above >= 1 since cdf[0] = 0 <= u

  const float cdf_b = __shfl(cdf, below);
  const float cdf_a = __shfl(cdf, above);
  const float bin_b = __shfl(bin, below);
  const float bin_a = __shfl(bin, above);
  float denom = cdf_a - cdf_b;
  if (denom < 1e-6f) denom = 1.0f;
  const float t = (u - cdf_b) / denom;
  const float fine = bin_b + t * (bin_a - bin_b + 1e-6f);

  // ---- stable rank-scatter merge of fine(64, unsorted) + coarse(64, sorted) ----
  ls_fine[wv][lane] = fine;
  ls_sv[wv][lane] = sv;
  __syncthreads();

  int pos_f = 0;
  int pos_c = lane;  // coarse: earlier coarse entries = own index (sorted, stable)
  const float4* ff = (const float4*)ls_fine[wv];
  const float4* cc = (const float4*)ls_sv[wv];
  #pragma unroll
  for (int it = 0; it < 16; ++it) {
    float4 f = ff[it];
    float4 c = cc[it];
    const int i0 = it * 4;
    pos_f += (int)((f.x < fine) || (f.x == fine && (i0 + 0) < lane));
    pos_f += (int)((f.y < fine) || (f.y == fine && (i0 + 1) < lane));
    pos_f += (int)((f.z < fine) || (f.z == fine && (i0 + 2) < lane));
    pos_f += (int)((f.w < fine) || (f.w == fine && (i0 + 3) < lane));
    pos_f += (int)(c.x < fine) + (int)(c.y < fine) + (int)(c.z < fine) + (int)(c.w < fine);
    pos_c += (int)(f.x <= sv) + (int)(f.y <= sv) + (int)(f.z <= sv) + (int)(f.w <= sv);
  }
  ls_srt[wv][pos_f] = fine;
  ls_srt[wv][pos_c] = sv;
  __syncthreads();

  // ---- outputs: pts (B,128,3), z (B,128), s (B,128) ----
  const float ox = rays_o[(size_t)ray * 3 + 0];
  const float oy = rays_o[(size_t)ray * 3 + 1];
  const float oz = rays_o[(size_t)ray * 3 + 2];
  const float dx = rays_d[(size_t)ray * 3 + 0];
  const float dy = rays_d[(size_t)ray * 3 + 1];
  const float dz = rays_d[(size_t)ray * 3 + 2];

  float* pts = out;
  float* zp = out + (size_t)nrays * 384;
  float* sp = zp + (size_t)nrays * 128;

  const float v0 = ls_srt[wv][lane];
  const float v1 = ls_srt[wv][lane + 64];
  const size_t zbase = (size_t)ray * 128;
  zp[zbase + lane] = v0;
  zp[zbase + 64 + lane] = v1;
  sp[zbase + lane] = v0;
  sp[zbase + 64 + lane] = v1;

  const size_t pbase = (size_t)ray * 384;
  #pragma unroll
  for (int tq = 0; tq < 6; ++tq) {
    const int idx = lane + 64 * tq;      // 0..383, coalesced dword stores
    const int si = idx / 3;
    const int cmp = idx - si * 3;
    const float zv = ls_srt[wv][si];
    const float oc = (cmp == 0) ? ox : ((cmp == 1) ? oy : oz);
    const float dc = (cmp == 0) ? dx : ((cmp == 1) ? dy : dz);
    pts[pbase + idx] = oc + dc * zv;
  }
}

extern "C" void kernel_launch(void* const* d_in, const int* in_sizes, int n_in,
                              void* d_out, int out_size, void* d_ws, size_t ws_size,
                              hipStream_t stream) {
  const float* rays_o = (const float*)d_in[0];
  const float* rays_d = (const float*)d_in[1];
  const float* s_vals = (const float*)d_in[2];
  const float* weights = (const float*)d_in[3];
  float* out = (float*)d_out;

  const int nrays = in_sizes[2] / 64;      // 131072
  const int blocks = (nrays + 3) / 4;      // 4 rays (waves) per 256-thread block

  newsampler_kernel<<<blocks, 256, 0, stream>>>(rays_o, rays_d, s_vals, weights,
                                                out, nrays);
}

// Round 7
// 110.062 us; speedup vs baseline: 2.2598x; 2.2598x over previous
//
#include <hip/hip_runtime.h>
#include <stdint.h>

// NeRF NewSampler: per-ray inverse-CDF fine sampling (JAX threefry-exact,
// partitionable XOR-fold stream: bits[i] = y0^y1 of cipher((0,42),(0,i))),
// register-only pipeline: bitonic sort of u-bits -> binary-search bin lookup
// -> bitonic MERGE with coarse samples -> direct register stores.
// No LDS arrays, no barriers. One wave (64 lanes) per ray; block = 4 waves.
//
// Correctness notes vs reference:
//  - u->fine map is identical per element; sorting u first only permutes
//    lanes (multiset of fine values bit-identical).
//  - fine(u_sorted) is monotone up to 1e-6 (bin-crossing overshoot), and
//    compare-exchange networks are 1-Lipschitz (sup-norm), so the merged
//    output differs from a true sort only among values within ~1e-6.
//  - binary search == searchsorted(side='right') on the same cdf values.

__device__ __forceinline__ uint32_t rotl32(uint32_t x, uint32_t d) {
  return (x << d) | (x >> (32u - d));
}

// JAX threefry2x32, key (0, 42). KAT-verified schedule. Returns y0 ^ y1.
__device__ __forceinline__ uint32_t threefry2x32_xor(uint32_t x0i, uint32_t x1i) {
  uint32_t x0 = x0i;
  uint32_t x1 = x1i;
  const uint32_t ks0 = 0u;
  const uint32_t ks1 = 42u;
  const uint32_t ks2 = 0x1BD11BDAu ^ 0u ^ 42u;  // 0x1BD11BF0
#define TF_ROUND(r) { x0 += x1; x1 = rotl32(x1, r); x1 ^= x0; }
  x0 += ks0; x1 += ks1;
  TF_ROUND(13) TF_ROUND(15) TF_ROUND(26) TF_ROUND(6)
  x0 += ks1; x1 += ks2 + 1u;
  TF_ROUND(17) TF_ROUND(29) TF_ROUND(16) TF_ROUND(24)
  x0 += ks2; x1 += ks0 + 2u;
  TF_ROUND(13) TF_ROUND(15) TF_ROUND(26) TF_ROUND(6)
  x0 += ks0; x1 += ks1 + 3u;
  TF_ROUND(17) TF_ROUND(29) TF_ROUND(16) TF_ROUND(24)
  x0 += ks1; x1 += ks2 + 4u;
  TF_ROUND(13) TF_ROUND(15) TF_ROUND(26) TF_ROUND(6)
  x0 += ks2; x1 += ks0 + 5u;
#undef TF_ROUND
  return x0 ^ x1;
}

struct F3 { float x, y, z; };  // 12B, align 4 -> contiguous per-lane stores

__global__ __launch_bounds__(256) void newsampler_kernel(
    const float* __restrict__ rays_o,
    const float* __restrict__ rays_d,
    const float* __restrict__ s_vals,
    const float* __restrict__ weights,
    float* __restrict__ out,
    int nrays)
{
  const int lane = threadIdx.x & 63;
  const int wv   = threadIdx.x >> 6;
  int ray = blockIdx.x * 4 + wv;
  if (ray >= nrays) ray = nrays - 1;

  // ---- coarse depth + weight (coalesced) ----
  const float sv = s_vals[(size_t)ray * 64 + lane];
  const float wt = weights[(size_t)ray * 64 + lane];

  // ---- bins: mid[j] = 0.5*(s[j]+s[j+1]), lanes 0..62 valid ----
  const float sv_next = __shfl_down(sv, 1);
  const float bin = 0.5f * (sv + sv_next);

  // ---- pdf over weights[1..62]+1e-6; cdf inclusive prefix (same numerics
  //      as the passing R6 kernel: xor-reduce then Hillis-Steele) ----
  const float wm = (lane >= 1 && lane <= 62) ? (wt + 1e-6f) : 0.0f;
  float tot = wm;
  #pragma unroll
  for (int s = 1; s < 64; s <<= 1) tot += __shfl_xor(tot, s);
  const float pdf = wm / tot;
  float cdf = pdf;  // lane l holds cdf_ref[l]; lane 0 == 0
  #pragma unroll
  for (int s = 1; s < 64; s <<= 1) {
    float t = __shfl_up(cdf, s);
    if (lane >= s) cdf += t;
  }
  const float cdfx = (lane < 62) ? cdf : 3.0e38f;  // search domain cdf[0:62]

  // ---- u bits (JAX partitionable XOR-fold), then 64-lane bitonic sort ----
  const uint32_t gi = (uint32_t)ray * 64u + (uint32_t)lane;
  uint32_t bits = threefry2x32_xor(0u, gi);
  #pragma unroll
  for (int k = 2; k <= 64; k <<= 1) {
    #pragma unroll
    for (int j = k >> 1; j >= 1; j >>= 1) {
      const uint32_t p = (uint32_t)__shfl_xor((int)bits, j);
      const bool keep_min = (((lane & k) != 0) == ((lane & j) != 0));
      const uint32_t mn = bits < p ? bits : p;
      const uint32_t mx = bits < p ? p : bits;
      bits = keep_min ? mn : mx;
    }
  }
  const float u = __uint_as_float((bits >> 9) | 0x3f800000u) - 1.0f;

  // ---- above = searchsorted(cdf[0:62], u, 'right') via 6-step binary
  //      search on register cdf (invariants: cdfx[lo]<=u < cdfx[hi]) ----
  int lo = 0, hi = 62;
  #pragma unroll
  for (int it = 0; it < 6; ++it) {
    const int mid = (lo + hi) >> 1;
    const float c = __shfl(cdfx, mid);
    const bool le = (c <= u);
    lo = le ? mid : lo;
    hi = le ? hi : mid;
  }
  const int below = lo, above = hi;

  const float cdf_b = __shfl(cdf, below);
  const float cdf_a = __shfl(cdf, above);   // real cdf (above<=62 valid)
  const float bin_b = __shfl(bin, below);
  const float bin_a = __shfl(bin, above);
  float denom = cdf_a - cdf_b;
  if (denom < 1e-6f) denom = 1.0f;
  const float t = (u - cdf_b) / denom;
  const float fine = bin_b + t * (bin_a - bin_b + 1e-6f);  // sorted (±1e-6)

  // ---- bitonic MERGE: concat(fine asc, sv desc) is bitonic ----
  const float svr = __shfl(sv, 63 - lane);   // sv reversed
  float mlo = fminf(fine, svr);
  float mhi = fmaxf(fine, svr);
  #pragma unroll
  for (int d = 32; d >= 1; d >>= 1) {
    const float pl = __shfl_xor(mlo, d);
    const float ph = __shfl_xor(mhi, d);
    const bool kmin = ((lane & d) == 0);
    mlo = kmin ? fminf(mlo, pl) : fmaxf(mlo, pl);
    mhi = kmin ? fminf(mhi, ph) : fmaxf(mhi, ph);
  }
  // merged[lane] = mlo, merged[64+lane] = mhi (ascending)

  // ---- outputs straight from registers ----
  const float ox = rays_o[(size_t)ray * 3 + 0];
  const float oy = rays_o[(size_t)ray * 3 + 1];
  const float oz = rays_o[(size_t)ray * 3 + 2];
  const float dx = rays_d[(size_t)ray * 3 + 0];
  const float dy = rays_d[(size_t)ray * 3 + 1];
  const float dz = rays_d[(size_t)ray * 3 + 2];

  float* pts = out;
  float* zp  = out + (size_t)nrays * 384;
  float* sp  = zp + (size_t)nrays * 128;

  const size_t zbase = (size_t)ray * 128;
  zp[zbase + lane]      = mlo;
  zp[zbase + 64 + lane] = mhi;
  sp[zbase + lane]      = mlo;
  sp[zbase + 64 + lane] = mhi;

  // pts: lane owns samples s=lane (mlo) and s=64+lane (mhi): 12B contiguous
  const size_t pbase = (size_t)ray * 384 + 3u * (uint32_t)lane;
  F3 a = { ox + dx * mlo, oy + dy * mlo, oz + dz * mlo };
  F3 b = { ox + dx * mhi, oy + dy * mhi, oz + dz * mhi };
  *(F3*)(pts + pbase)       = a;
  *(F3*)(pts + pbase + 192) = b;
}

extern "C" void kernel_launch(void* const* d_in, const int* in_sizes, int n_in,
                              void* d_out, int out_size, void* d_ws, size_t ws_size,
                              hipStream_t stream) {
  const float* rays_o  = (const float*)d_in[0];
  const float* rays_d  = (const float*)d_in[1];
  const float* s_vals  = (const float*)d_in[2];
  const float* weights = (const float*)d_in[3];
  float* out = (float*)d_out;

  const int nrays = in_sizes[2] / 64;      // 131072
  const int blocks = (nrays + 3) / 4;      // 4 rays (waves) per 256-thread block

  newsampler_kernel<<<blocks, 256, 0, stream>>>(rays_o, rays_d, s_vals, weights,
                                                out, nrays);
}

// Round 12
// 100.398 us; speedup vs baseline: 2.4774x; 1.0963x over previous
//
#include <hip/hip_runtime.h>
#include <stdint.h>

// NeRF NewSampler: per-ray inverse-CDF fine sampling (JAX threefry-exact,
// partitionable XOR-fold stream: bits[i] = y0^y1 of cipher((0,42),(0,i))),
// register-only pipeline, swizzle-based cross-lane ops (immediate patterns,
// no per-lane index VALU): Sklansky scan -> bitonic sort of u-bits ->
// binary-search bin lookup (unnormalized cdf) -> bitonic merge with coarse
// samples -> direct register stores. One wave per ray; block = 4 waves.
//
// ds_swizzle bit-mode: src_lane = ((lane & and) | or) ^ xor,
//                      imm = (xor<<10) | (or<<5) | and   (bit15 = 0)

__device__ __forceinline__ uint32_t rotl32(uint32_t x, uint32_t d) {
  return (x << d) | (x >> (32u - d));  // -> v_alignbit_b32
}

// JAX threefry2x32, key (0, 42). KAT-verified schedule. Returns y0 ^ y1.
__device__ __forceinline__ uint32_t threefry2x32_xor(uint32_t x0i, uint32_t x1i) {
  uint32_t x0 = x0i;
  uint32_t x1 = x1i;
  const uint32_t ks0 = 0u;
  const uint32_t ks1 = 42u;
  const uint32_t ks2 = 0x1BD11BDAu ^ 0u ^ 42u;  // 0x1BD11BF0
#define TF_ROUND(r) { x0 += x1; x1 = rotl32(x1, r); x1 ^= x0; }
  x0 += ks0; x1 += ks1;
  TF_ROUND(13) TF_ROUND(15) TF_ROUND(26) TF_ROUND(6)
  x0 += ks1; x1 += ks2 + 1u;
  TF_ROUND(17) TF_ROUND(29) TF_ROUND(16) TF_ROUND(24)
  x0 += ks2; x1 += ks0 + 2u;
  TF_ROUND(13) TF_ROUND(15) TF_ROUND(26) TF_ROUND(6)
  x0 += ks0; x1 += ks1 + 3u;
  TF_ROUND(17) TF_ROUND(29) TF_ROUND(16) TF_ROUND(24)
  x0 += ks1; x1 += ks2 + 4u;
  TF_ROUND(13) TF_ROUND(15) TF_ROUND(26) TF_ROUND(6)
  x0 += ks2; x1 += ks0 + 5u;
#undef TF_ROUND
  return x0 ^ x1;
}

// ---- swizzle helpers: immediate-pattern cross-lane within 32-lane halves ----
template <int IMM>
__device__ __forceinline__ uint32_t swzu(uint32_t x) {
  return (uint32_t)__builtin_amdgcn_ds_swizzle((int)x, IMM);
}
template <int IMM>
__device__ __forceinline__ float swzf(float x) {
  return __int_as_float(__builtin_amdgcn_ds_swizzle(__float_as_int(x), IMM));
}
// xor-lane exchange; J<=16 via swizzle (bit mode: (J<<10)|0x1F), J=32 via shfl
template <int J>
__device__ __forceinline__ uint32_t xlu(uint32_t x) {
  if constexpr (J == 32) return (uint32_t)__shfl_xor((int)x, 32);
  else return swzu<(J << 10) | 31>(x);
}
template <int J>
__device__ __forceinline__ float xlf(float x) {
  if constexpr (J == 32) return __shfl_xor(x, 32);
  else return swzf<(J << 10) | 31>(x);
}

// ---- bitonic sort (ascending) of one u32 per lane, 64 lanes ----
template <int K, int J>
struct SortStage {
  static __device__ __forceinline__ void run(uint32_t& b, int lane) {
    const uint32_t p = xlu<J>(b);
    const bool keep_min = (((lane & K) != 0) == ((lane & J) != 0));
    const uint32_t mn = b < p ? b : p;
    const uint32_t mx = b < p ? p : b;
    b = keep_min ? mn : mx;
    if constexpr (J > 1) SortStage<K, J / 2>::run(b, lane);
  }
};
template <int K>
struct SortPass {
  static __device__ __forceinline__ void run(uint32_t& b, int lane) {
    SortStage<K, K / 2>::run(b, lane);
    if constexpr (K < 64) SortPass<K * 2>::run(b, lane);
  }
};

// ---- bitonic merge cleanup for the 128-element (mlo,mhi) pair ----
template <int D>
struct MergeStage {
  static __device__ __forceinline__ void run(float& mlo, float& mhi, int lane) {
    const float pl = xlf<D>(mlo);
    const float ph = xlf<D>(mhi);
    const bool kmin = ((lane & D) == 0);
    mlo = kmin ? fminf(mlo, pl) : fmaxf(mlo, pl);
    mhi = kmin ? fminf(mhi, ph) : fmaxf(mhi, ph);
    if constexpr (D > 1) MergeStage<D / 2>::run(mlo, mhi, lane);
  }
};

struct F3 { float x, y, z; };  // 12B per-lane contiguous store

__global__ __launch_bounds__(256) void newsampler_kernel(
    const float* __restrict__ rays_o,
    const float* __restrict__ rays_d,
    const float* __restrict__ s_vals,
    const float* __restrict__ weights,
    float* __restrict__ out,
    int nrays)
{
  const int lane = threadIdx.x & 63;
  const int wv   = threadIdx.x >> 6;
  int ray = blockIdx.x * 4 + wv;
  if (ray >= nrays) ray = nrays - 1;

  // ---- coarse depth + weight (coalesced) ----
  const float sv = s_vals[(size_t)ray * 64 + lane];
  const float wt = weights[(size_t)ray * 64 + lane];

  // ---- bins: mid[j] = 0.5*(s[j]+s[j+1]) ----
  const float sv_next = __shfl_down(sv, 1);
  const float bin = 0.5f * (sv + sv_next);

  // ---- unnormalized cdf: Sklansky inclusive scan of masked weights ----
  // partner(s) = (lane & ~s) | (s-1): swizzle imm = ((s-1)<<5) | ((~s)&31)
  const float wm = (lane >= 1 && lane <= 62) ? (wt + 1e-6f) : 0.0f;
  float cw = wm;
  { float t;
    t = swzf<0x01E>(cw); cw = (lane & 1)  ? cw + t : cw;
    t = swzf<0x03D>(cw); cw = (lane & 2)  ? cw + t : cw;
    t = swzf<0x07B>(cw); cw = (lane & 4)  ? cw + t : cw;
    t = swzf<0x0F7>(cw); cw = (lane & 8)  ? cw + t : cw;
    t = swzf<0x1EF>(cw); cw = (lane & 16) ? cw + t : cw;
    const float lo31 = __int_as_float(
        __builtin_amdgcn_readlane(__float_as_int(cw), 31));
    cw = (lane & 32) ? cw + lo31 : cw;
  }
  const float tot = __int_as_float(
      __builtin_amdgcn_readlane(__float_as_int(cw), 63));
  const float cwx = (lane < 62) ? cw : 3.0e38f;  // search domain cdf[0:62]

  // ---- u bits (JAX partitionable XOR-fold), bitonic sort across wave ----
  const uint32_t gi = (uint32_t)ray * 64u + (uint32_t)lane;
  uint32_t bits = threefry2x32_xor(0u, gi);
  SortPass<2>::run(bits, lane);
  const float u = __uint_as_float((bits >> 9) | 0x3f800000u) - 1.0f;
  const float ut = u * tot;  // compare in unnormalized units

  // ---- above = searchsorted(cdf[0:62], u, 'right'): 6-step binary search
  //      invariants: cwx[lo] <= ut < cwx[hi] ----
  int lo = 0, hi = 62;
  #pragma unroll
  for (int it = 0; it < 6; ++it) {
    const int mid = (lo + hi) >> 1;
    const float c = __shfl(cwx, mid);
    const bool le = (c <= ut);
    lo = le ? mid : lo;
    hi = le ? hi : mid;
  }

  const float cw_b = __shfl(cw, lo);
  const float cw_a = __shfl(cw, hi);
  const float bin_b = __shfl(bin, lo);
  const float bin_a = __shfl(bin, hi);
  float denom = cw_a - cw_b;                 // = (cdf_a-cdf_b)*tot
  if (denom < 1e-6f * tot) denom = tot;      // ref: denom<1e-6 -> 1 (x tot)
  const float t = (ut - cw_b) / denom;
  const float fine = bin_b + t * (bin_a - bin_b + 1e-6f);  // sorted (±1e-6)

  // ---- bitonic merge: concat(fine asc, sv desc) is bitonic ----
  // sv[63-lane] = xor-31 within half (imm 0x7C1F), then xor-32 across halves
  const float svr = xlf<32>(swzf<0x7C1F>(sv));
  float mlo = fminf(fine, svr);
  float mhi = fmaxf(fine, svr);
  MergeStage<32>::run(mlo, mhi, lane);
  // merged[lane] = mlo, merged[64+lane] = mhi (ascending)

  // ---- outputs straight from registers ----
  const float ox = rays_o[(size_t)ray * 3 + 0];
  const float oy = rays_o[(size_t)ray * 3 + 1];
  const float oz = rays_o[(size_t)ray * 3 + 2];
  const float dx = rays_d[(size_t)ray * 3 + 0];
  const float dy = rays_d[(size_t)ray * 3 + 1];
  const float dz = rays_d[(size_t)ray * 3 + 2];

  float* pts = out;
  float* zp  = out + (size_t)nrays * 384;
  float* sp  = zp + (size_t)nrays * 128;

  const size_t zbase = (size_t)ray * 128;
  zp[zbase + lane]      = mlo;
  zp[zbase + 64 + lane] = mhi;
  sp[zbase + lane]      = mlo;
  sp[zbase + 64 + lane] = mhi;

  const size_t pbase = (size_t)ray * 384 + 3u * (uint32_t)lane;
  F3 a = { ox + dx * mlo, oy + dy * mlo, oz + dz * mlo };
  F3 b = { ox + dx * mhi, oy + dy * mhi, oz + dz * mhi };
  *(F3*)(pts + pbase)       = a;
  *(F3*)(pts + pbase + 192) = b;
}

extern "C" void kernel_launch(void* const* d_in, const int* in_sizes, int n_in,
                              void* d_out, int out_size, void* d_ws, size_t ws_size,
                              hipStream_t stream) {
  const float* rays_o  = (const float*)d_in[0];
  const float* rays_d  = (const float*)d_in[1];
  const float* s_vals  = (const float*)d_in[2];
  const float* weights = (const float*)d_in[3];
  float* out = (float*)d_out;

  const int nrays = in_sizes[2] / 64;      // 131072
  const int blocks = (nrays + 3) / 4;      // 4 rays (waves) per 256-thread block

  newsampler_kernel<<<blocks, 256, 0, stream>>>(rays_o, rays_d, s_vals, weights,
                                                out, nrays);
}

// Round 13
// 96.184 us; speedup vs baseline: 2.5859x; 1.0438x over previous
//
#include <hip/hip_runtime.h>
#include <stdint.h>

// NeRF NewSampler: per-ray inverse-CDF fine sampling (JAX threefry-exact,
// partitionable XOR-fold stream: bits[i] = y0^y1 of cipher((0,42),(0,i))),
// register-only pipeline. Cross-lane ops now use DPP (VALU pipe, ~2cyc) where
// a row-pattern exists, ds_swizzle only for xor-4/8/16, bpermute only for the
// data-dependent search/gather. One wave per ray; block = 4 waves.
//
// ds_swizzle bit-mode: src = ((lane & and) | or) ^ xor; imm = xor<<10|or<<5|and
// DPP ctrl: quad_perm = p0|p1<<2|p2<<4|p3<<6; row_bcast15=0x142, bcast31=0x143

__device__ __forceinline__ uint32_t rotl32(uint32_t x, uint32_t d) {
  return (x << d) | (x >> (32u - d));  // -> v_alignbit_b32
}

// JAX threefry2x32, key (0, 42). KAT-verified schedule. Returns y0 ^ y1.
__device__ __forceinline__ uint32_t threefry2x32_xor(uint32_t x0i, uint32_t x1i) {
  uint32_t x0 = x0i;
  uint32_t x1 = x1i;
  const uint32_t ks0 = 0u;
  const uint32_t ks1 = 42u;
  const uint32_t ks2 = 0x1BD11BDAu ^ 0u ^ 42u;  // 0x1BD11BF0
#define TF_ROUND(r) { x0 += x1; x1 = rotl32(x1, r); x1 ^= x0; }
  x0 += ks0; x1 += ks1;
  TF_ROUND(13) TF_ROUND(15) TF_ROUND(26) TF_ROUND(6)
  x0 += ks1; x1 += ks2 + 1u;
  TF_ROUND(17) TF_ROUND(29) TF_ROUND(16) TF_ROUND(24)
  x0 += ks2; x1 += ks0 + 2u;
  TF_ROUND(13) TF_ROUND(15) TF_ROUND(26) TF_ROUND(6)
  x0 += ks0; x1 += ks1 + 3u;
  TF_ROUND(17) TF_ROUND(29) TF_ROUND(16) TF_ROUND(24)
  x0 += ks1; x1 += ks2 + 4u;
  TF_ROUND(13) TF_ROUND(15) TF_ROUND(26) TF_ROUND(6)
  x0 += ks2; x1 += ks0 + 5u;
#undef TF_ROUND
  return x0 ^ x1;
}

// ---- DPP helpers (VALU-pipe lane exchange, immediate control) ----
template <int CTRL>
__device__ __forceinline__ uint32_t dppu(uint32_t x) {
  return (uint32_t)__builtin_amdgcn_update_dpp((int)x, (int)x, CTRL, 0xF, 0xF, true);
}
template <int CTRL>
__device__ __forceinline__ float dppf(float x) {
  return __int_as_float(__builtin_amdgcn_update_dpp(
      __float_as_int(x), __float_as_int(x), CTRL, 0xF, 0xF, true));
}

// ---- swizzle helpers (LDS pipe; only where no DPP pattern exists) ----
template <int IMM>
__device__ __forceinline__ uint32_t swzu(uint32_t x) {
  return (uint32_t)__builtin_amdgcn_ds_swizzle((int)x, IMM);
}
template <int IMM>
__device__ __forceinline__ float swzf(float x) {
  return __int_as_float(__builtin_amdgcn_ds_swizzle(__float_as_int(x), IMM));
}

// xor-lane exchange: J=1,2 DPP quad_perm; J=4,8,16 swizzle; J=32 shfl (bpermute)
template <int J>
__device__ __forceinline__ uint32_t xlu(uint32_t x) {
  if constexpr (J == 1)  return dppu<0xB1>(x);        // quad_perm [1,0,3,2]
  else if constexpr (J == 2) return dppu<0x4E>(x);    // quad_perm [2,3,0,1]
  else if constexpr (J == 32) return (uint32_t)__shfl_xor((int)x, 32);
  else return swzu<(J << 10) | 31>(x);
}
template <int J>
__device__ __forceinline__ float xlf(float x) {
  if constexpr (J == 1)  return dppf<0xB1>(x);
  else if constexpr (J == 2) return dppf<0x4E>(x);
  else if constexpr (J == 32) return __shfl_xor(x, 32);
  else return swzf<(J << 10) | 31>(x);
}

// ---- bitonic sort (ascending) of one u32 per lane, 64 lanes ----
template <int K, int J>
struct SortStage {
  static __device__ __forceinline__ void run(uint32_t& b, int lane) {
    const uint32_t p = xlu<J>(b);
    const bool keep_min = (((lane & K) != 0) == ((lane & J) != 0));
    const uint32_t mn = b < p ? b : p;
    const uint32_t mx = b < p ? p : b;
    b = keep_min ? mn : mx;
    if constexpr (J > 1) SortStage<K, J / 2>::run(b, lane);
  }
};
template <int K>
struct SortPass {
  static __device__ __forceinline__ void run(uint32_t& b, int lane) {
    SortStage<K, K / 2>::run(b, lane);
    if constexpr (K < 64) SortPass<K * 2>::run(b, lane);
  }
};

// ---- bitonic merge cleanup for the 128-element (mlo,mhi) pair ----
template <int D>
struct MergeStage {
  static __device__ __forceinline__ void run(float& mlo, float& mhi, int lane) {
    const float pl = xlf<D>(mlo);
    const float ph = xlf<D>(mhi);
    const bool kmin = ((lane & D) == 0);
    mlo = kmin ? fminf(mlo, pl) : fmaxf(mlo, pl);
    mhi = kmin ? fminf(mhi, ph) : fmaxf(mhi, ph);
    if constexpr (D > 1) MergeStage<D / 2>::run(mlo, mhi, lane);
  }
};

struct F3 { float x, y, z; };  // 12B per-lane contiguous store

__global__ __launch_bounds__(256) void newsampler_kernel(
    const float* __restrict__ rays_o,
    const float* __restrict__ rays_d,
    const float* __restrict__ s_vals,
    const float* __restrict__ weights,
    float* __restrict__ out,
    int nrays)
{
  const int lane = threadIdx.x & 63;
  const int wv   = threadIdx.x >> 6;
  int ray = blockIdx.x * 4 + wv;
  if (ray >= nrays) ray = nrays - 1;

  // ---- coarse depth + weight (coalesced) ----
  const float sv = s_vals[(size_t)ray * 64 + lane];
  const float wt = weights[(size_t)ray * 64 + lane];

  // ---- bins: mid[j] = 0.5*(s[j]+s[j+1]) ----
  const float sv_next = __shfl_down(sv, 1);
  const float bin = 0.5f * (sv + sv_next);

  // ---- unnormalized cdf: Sklansky inclusive scan, partner = (lane&~s)|(s-1)
  //      s=1: quad[0,0,2,2]=0xA0; s=2: quad[1,1,1,1]=0x55; s=4,8: swizzle;
  //      s=16: row_bcast15 (lane15->16..31, lane47->48..63);
  //      s=32: row_bcast31 (lane31->32..63). Zero-filled lanes are masked. ----
  const float wm = (lane >= 1 && lane <= 62) ? (wt + 1e-6f) : 0.0f;
  float cw = wm;
  { float t;
    t = dppf<0xA0>(cw);  cw = (lane & 1)  ? cw + t : cw;
    t = dppf<0x55>(cw);  cw = (lane & 2)  ? cw + t : cw;
    t = swzf<0x07B>(cw); cw = (lane & 4)  ? cw + t : cw;
    t = swzf<0x0F7>(cw); cw = (lane & 8)  ? cw + t : cw;
    t = dppf<0x142>(cw); cw = (lane & 16) ? cw + t : cw;
    t = dppf<0x143>(cw); cw = (lane & 32) ? cw + t : cw;
  }
  const float tot = __int_as_float(
      __builtin_amdgcn_readlane(__float_as_int(cw), 63));
  const float cwx = (lane < 62) ? cw : 3.0e38f;  // search domain cdf[0:62]

  // ---- u bits (JAX partitionable XOR-fold), bitonic sort across wave ----
  const uint32_t gi = (uint32_t)ray * 64u + (uint32_t)lane;
  uint32_t bits = threefry2x32_xor(0u, gi);
  SortPass<2>::run(bits, lane);
  const float u = __uint_as_float((bits >> 9) | 0x3f800000u) - 1.0f;
  const float ut = u * tot;  // compare in unnormalized units

  // ---- above = searchsorted(cdf[0:62], u, 'right'): 6-step binary search
  //      invariants: cwx[lo] <= ut < cwx[hi] ----
  int lo = 0, hi = 62;
  #pragma unroll
  for (int it = 0; it < 6; ++it) {
    const int mid = (lo + hi) >> 1;
    const float c = __shfl(cwx, mid);
    const bool le = (c <= ut);
    lo = le ? mid : lo;
    hi = le ? hi : mid;
  }

  const float cw_b = __shfl(cw, lo);
  const float cw_a = __shfl(cw, hi);
  const float bin_b = __shfl(bin, lo);
  const float bin_a = __shfl(bin, hi);
  float denom = cw_a - cw_b;                 // = (cdf_a-cdf_b)*tot
  if (denom < 1e-6f * tot) denom = tot;      // ref: denom<1e-6 -> 1 (x tot)
  const float t = (ut - cw_b) / denom;
  const float fine = bin_b + t * (bin_a - bin_b + 1e-6f);  // sorted (±1e-6)

  // ---- bitonic merge: concat(fine asc, sv desc) is bitonic ----
  // sv[63-lane]: xor-31 within half (swizzle 0x7C1F), then xor-32 across halves
  const float svr = xlf<32>(swzf<0x7C1F>(sv));
  float mlo = fminf(fine, svr);
  float mhi = fmaxf(fine, svr);
  MergeStage<32>::run(mlo, mhi, lane);
  // merged[lane] = mlo, merged[64+lane] = mhi (ascending)

  // ---- outputs straight from registers ----
  const float ox = rays_o[(size_t)ray * 3 + 0];
  const float oy = rays_o[(size_t)ray * 3 + 1];
  const float oz = rays_o[(size_t)ray * 3 + 2];
  const float dx = rays_d[(size_t)ray * 3 + 0];
  const float dy = rays_d[(size_t)ray * 3 + 1];
  const float dz = rays_d[(size_t)ray * 3 + 2];

  float* pts = out;
  float* zp  = out + (size_t)nrays * 384;
  float* sp  = zp + (size_t)nrays * 128;

  const size_t zbase = (size_t)ray * 128;
  zp[zbase + lane]      = mlo;
  zp[zbase + 64 + lane] = mhi;
  sp[zbase + lane]      = mlo;
  sp[zbase + 64 + lane] = mhi;

  const size_t pbase = (size_t)ray * 384 + 3u * (uint32_t)lane;
  F3 a = { ox + dx * mlo, oy + dy * mlo, oz + dz * mlo };
  F3 b = { ox + dx * mhi, oy + dy * mhi, oz + dz * mhi };
  *(F3*)(pts + pbase)       = a;
  *(F3*)(pts + pbase + 192) = b;
}

extern "C" void kernel_launch(void* const* d_in, const int* in_sizes, int n_in,
                              void* d_out, int out_size, void* d_ws, size_t ws_size,
                              hipStream_t stream) {
  const float* rays_o  = (const float*)d_in[0];
  const float* rays_d  = (const float*)d_in[1];
  const float* s_vals  = (const float*)d_in[2];
  const float* weights = (const float*)d_in[3];
  float* out = (float*)d_out;

  const int nrays = in_sizes[2] / 64;      // 131072
  const int blocks = (nrays + 3) / 4;      // 4 rays (waves) per 256-thread block

  newsampler_kernel<<<blocks, 256, 0, stream>>>(rays_o, rays_d, s_vals, weights,
                                                out, nrays);
}

// Round 14
// 86.074 us; speedup vs baseline: 2.8897x; 1.1175x over previous
//
#include <hip/hip_runtime.h>
#include <stdint.h>

// NeRF NewSampler: per-ray inverse-CDF fine sampling (JAX threefry-exact,
// partitionable XOR-fold stream: bits[i] = y0^y1 of cipher((0,42),(0,i))),
// register-only pipeline. This round: 2 RAYS PER WAVE, stage-interleaved
// (ILP-2) to hide the sort/search serial latency chains. Cross-lane ops:
// DPP where a row-pattern exists, ds_swizzle for xor-4/8/16, bpermute for
// data-dependent gathers. Block = 256 threads = 4 waves = 8 rays.
//
// ds_swizzle bit-mode: src = ((lane & and) | or) ^ xor; imm = xor<<10|or<<5|and
// DPP ctrl: quad_perm = p0|p1<<2|p2<<4|p3<<6; row_bcast15=0x142, bcast31=0x143

__device__ __forceinline__ uint32_t rotl32(uint32_t x, uint32_t d) {
  return (x << d) | (x >> (32u - d));  // -> v_alignbit_b32
}

// JAX threefry2x32, key (0, 42), ILP-2: two counters at once.
__device__ __forceinline__ void threefry2x32_xor2(uint32_t c0, uint32_t c1,
                                                  uint32_t* r0, uint32_t* r1) {
  const uint32_t ks0 = 0u;
  const uint32_t ks1 = 42u;
  const uint32_t ks2 = 0x1BD11BDAu ^ 0u ^ 42u;  // 0x1BD11BF0
  uint32_t a0 = 0u, b0 = c0;
  uint32_t a1 = 0u, b1 = c1;
#define TF_R2(r) { a0 += b0; a1 += b1; b0 = rotl32(b0, r); b1 = rotl32(b1, r); \
                   b0 ^= a0; b1 ^= a1; }
  a0 += ks0; b0 += ks1;  a1 += ks0; b1 += ks1;
  TF_R2(13) TF_R2(15) TF_R2(26) TF_R2(6)
  a0 += ks1; b0 += ks2 + 1u;  a1 += ks1; b1 += ks2 + 1u;
  TF_R2(17) TF_R2(29) TF_R2(16) TF_R2(24)
  a0 += ks2; b0 += ks0 + 2u;  a1 += ks2; b1 += ks0 + 2u;
  TF_R2(13) TF_R2(15) TF_R2(26) TF_R2(6)
  a0 += ks0; b0 += ks1 + 3u;  a1 += ks0; b1 += ks1 + 3u;
  TF_R2(17) TF_R2(29) TF_R2(16) TF_R2(24)
  a0 += ks1; b0 += ks2 + 4u;  a1 += ks1; b1 += ks2 + 4u;
  TF_R2(13) TF_R2(15) TF_R2(26) TF_R2(6)
  a0 += ks2; b0 += ks0 + 5u;  a1 += ks2; b1 += ks0 + 5u;
#undef TF_R2
  *r0 = a0 ^ b0;
  *r1 = a1 ^ b1;
}

// ---- DPP / swizzle helpers ----
template <int CTRL>
__device__ __forceinline__ uint32_t dppu(uint32_t x) {
  return (uint32_t)__builtin_amdgcn_update_dpp((int)x, (int)x, CTRL, 0xF, 0xF, true);
}
template <int CTRL>
__device__ __forceinline__ float dppf(float x) {
  return __int_as_float(__builtin_amdgcn_update_dpp(
      __float_as_int(x), __float_as_int(x), CTRL, 0xF, 0xF, true));
}
template <int IMM>
__device__ __forceinline__ uint32_t swzu(uint32_t x) {
  return (uint32_t)__builtin_amdgcn_ds_swizzle((int)x, IMM);
}
template <int IMM>
__device__ __forceinline__ float swzf(float x) {
  return __int_as_float(__builtin_amdgcn_ds_swizzle(__float_as_int(x), IMM));
}
template <int J>
__device__ __forceinline__ uint32_t xlu(uint32_t x) {
  if constexpr (J == 1)  return dppu<0xB1>(x);        // quad_perm [1,0,3,2]
  else if constexpr (J == 2) return dppu<0x4E>(x);    // quad_perm [2,3,0,1]
  else if constexpr (J == 32) return (uint32_t)__shfl_xor((int)x, 32);
  else return swzu<(J << 10) | 31>(x);
}
template <int J>
__device__ __forceinline__ float xlf(float x) {
  if constexpr (J == 1)  return dppf<0xB1>(x);
  else if constexpr (J == 2) return dppf<0x4E>(x);
  else if constexpr (J == 32) return __shfl_xor(x, 32);
  else return swzf<(J << 10) | 31>(x);
}

// ---- bitonic sort (ascending), ILP-2: two independent u32 streams ----
template <int K, int J>
struct SortStage {
  static __device__ __forceinline__ void run(uint32_t b[2], int lane) {
    const uint32_t p0 = xlu<J>(b[0]);
    const uint32_t p1 = xlu<J>(b[1]);
    const bool keep_min = (((lane & K) != 0) == ((lane & J) != 0));
    const uint32_t mn0 = b[0] < p0 ? b[0] : p0;
    const uint32_t mx0 = b[0] < p0 ? p0 : b[0];
    const uint32_t mn1 = b[1] < p1 ? b[1] : p1;
    const uint32_t mx1 = b[1] < p1 ? p1 : b[1];
    b[0] = keep_min ? mn0 : mx0;
    b[1] = keep_min ? mn1 : mx1;
    if constexpr (J > 1) SortStage<K, J / 2>::run(b, lane);
  }
};
template <int K>
struct SortPass {
  static __device__ __forceinline__ void run(uint32_t b[2], int lane) {
    SortStage<K, K / 2>::run(b, lane);
    if constexpr (K < 64) SortPass<K * 2>::run(b, lane);
  }
};

// ---- bitonic merge cleanup, ILP-2 on (mlo,mhi) pairs ----
template <int D>
struct MergeStage {
  static __device__ __forceinline__ void run(float mlo[2], float mhi[2], int lane) {
    const float pl0 = xlf<D>(mlo[0]);
    const float ph0 = xlf<D>(mhi[0]);
    const float pl1 = xlf<D>(mlo[1]);
    const float ph1 = xlf<D>(mhi[1]);
    const bool kmin = ((lane & D) == 0);
    mlo[0] = kmin ? fminf(mlo[0], pl0) : fmaxf(mlo[0], pl0);
    mhi[0] = kmin ? fminf(mhi[0], ph0) : fmaxf(mhi[0], ph0);
    mlo[1] = kmin ? fminf(mlo[1], pl1) : fmaxf(mlo[1], pl1);
    mhi[1] = kmin ? fminf(mhi[1], ph1) : fmaxf(mhi[1], ph1);
    if constexpr (D > 1) MergeStage<D / 2>::run(mlo, mhi, lane);
  }
};

struct F3 { float x, y, z; };  // 12B per-lane contiguous store

__global__ __launch_bounds__(256) void newsampler_kernel(
    const float* __restrict__ rays_o,
    const float* __restrict__ rays_d,
    const float* __restrict__ s_vals,
    const float* __restrict__ weights,
    float* __restrict__ out,
    int nrays)
{
  const int lane = threadIdx.x & 63;
  const int wv   = threadIdx.x >> 6;
  // wave handles rays r[0], r[1] (adjacent)
  int rbase = (blockIdx.x * 4 + wv) * 2;
  if (rbase >= nrays) rbase = 0;  // nrays % 8 == 0 in practice
  const int r[2] = { rbase, rbase + 1 };

  // ---- loads (coalesced, both rays) ----
  float sv[2], wt[2];
  #pragma unroll
  for (int i = 0; i < 2; ++i) {
    sv[i] = s_vals[(size_t)r[i] * 64 + lane];
    wt[i] = weights[(size_t)r[i] * 64 + lane];
  }

  // ---- bins ----
  float bin[2];
  #pragma unroll
  for (int i = 0; i < 2; ++i) {
    const float nx = __shfl_down(sv[i], 1);
    bin[i] = 0.5f * (sv[i] + nx);
  }

  // ---- unnormalized cdf: Sklansky scan (ILP-2) ----
  const bool inw = (lane >= 1 && lane <= 62);
  float cw[2];
  cw[0] = inw ? (wt[0] + 1e-6f) : 0.0f;
  cw[1] = inw ? (wt[1] + 1e-6f) : 0.0f;
  { float t0, t1;
    t0 = dppf<0xA0>(cw[0]);  t1 = dppf<0xA0>(cw[1]);
    if (lane & 1)  { cw[0] += t0; cw[1] += t1; }
    t0 = dppf<0x55>(cw[0]);  t1 = dppf<0x55>(cw[1]);
    if (lane & 2)  { cw[0] += t0; cw[1] += t1; }
    t0 = swzf<0x07B>(cw[0]); t1 = swzf<0x07B>(cw[1]);
    if (lane & 4)  { cw[0] += t0; cw[1] += t1; }
    t0 = swzf<0x0F7>(cw[0]); t1 = swzf<0x0F7>(cw[1]);
    if (lane & 8)  { cw[0] += t0; cw[1] += t1; }
    t0 = dppf<0x142>(cw[0]); t1 = dppf<0x142>(cw[1]);
    if (lane & 16) { cw[0] += t0; cw[1] += t1; }
    t0 = dppf<0x143>(cw[0]); t1 = dppf<0x143>(cw[1]);
    if (lane & 32) { cw[0] += t0; cw[1] += t1; }
  }
  float tot[2], cwx[2];
  #pragma unroll
  for (int i = 0; i < 2; ++i) {
    tot[i] = __int_as_float(__builtin_amdgcn_readlane(__float_as_int(cw[i]), 63));
    cwx[i] = (lane < 62) ? cw[i] : 3.0e38f;
  }

  // ---- u bits (XOR-fold threefry), bitonic sort (ILP-2) ----
  uint32_t bits[2];
  threefry2x32_xor2((uint32_t)r[0] * 64u + (uint32_t)lane,
                    (uint32_t)r[1] * 64u + (uint32_t)lane,
                    &bits[0], &bits[1]);
  SortPass<2>::run(bits, lane);
  float ut[2];
  #pragma unroll
  for (int i = 0; i < 2; ++i) {
    const float u = __uint_as_float((bits[i] >> 9) | 0x3f800000u) - 1.0f;
    ut[i] = u * tot[i];
  }

  // ---- binary search searchsorted(cdf[0:62], 'right') (ILP-2) ----
  int lo0 = 0, hi0 = 62, lo1 = 0, hi1 = 62;
  #pragma unroll
  for (int it = 0; it < 6; ++it) {
    const int m0 = (lo0 + hi0) >> 1;
    const int m1 = (lo1 + hi1) >> 1;
    const float c0 = __shfl(cwx[0], m0);
    const float c1 = __shfl(cwx[1], m1);
    const bool le0 = (c0 <= ut[0]);
    const bool le1 = (c1 <= ut[1]);
    lo0 = le0 ? m0 : lo0;  hi0 = le0 ? hi0 : m0;
    lo1 = le1 ? m1 : lo1;  hi1 = le1 ? hi1 : m1;
  }

  float fine[2];
  {
    const float cb0 = __shfl(cw[0], lo0),  cb1 = __shfl(cw[1], lo1);
    const float ca0 = __shfl(cw[0], hi0),  ca1 = __shfl(cw[1], hi1);
    const float bb0 = __shfl(bin[0], lo0), bb1 = __shfl(bin[1], lo1);
    const float ba0 = __shfl(bin[0], hi0), ba1 = __shfl(bin[1], hi1);
    float d0 = ca0 - cb0;
    float d1 = ca1 - cb1;
    if (d0 < 1e-6f * tot[0]) d0 = tot[0];
    if (d1 < 1e-6f * tot[1]) d1 = tot[1];
    const float t0 = (ut[0] - cb0) / d0;
    const float t1 = (ut[1] - cb1) / d1;
    fine[0] = bb0 + t0 * (ba0 - bb0 + 1e-6f);
    fine[1] = bb1 + t1 * (ba1 - bb1 + 1e-6f);
  }

  // ---- bitonic merge: concat(fine asc, sv desc) (ILP-2) ----
  float mlo[2], mhi[2];
  #pragma unroll
  for (int i = 0; i < 2; ++i) {
    const float svr = xlf<32>(swzf<0x7C1F>(sv[i]));  // sv[63-lane]
    mlo[i] = fminf(fine[i], svr);
    mhi[i] = fmaxf(fine[i], svr);
  }
  MergeStage<32>::run(mlo, mhi, lane);
  // merged[lane] = mlo, merged[64+lane] = mhi (ascending), per ray

  // ---- outputs ----
  float* pts = out;
  float* zp  = out + (size_t)nrays * 384;
  float* sp  = zp + (size_t)nrays * 128;

  #pragma unroll
  for (int i = 0; i < 2; ++i) {
    const float ox = rays_o[(size_t)r[i] * 3 + 0];
    const float oy = rays_o[(size_t)r[i] * 3 + 1];
    const float oz = rays_o[(size_t)r[i] * 3 + 2];
    const float dx = rays_d[(size_t)r[i] * 3 + 0];
    const float dy = rays_d[(size_t)r[i] * 3 + 1];
    const float dz = rays_d[(size_t)r[i] * 3 + 2];

    const size_t zbase = (size_t)r[i] * 128;
    zp[zbase + lane]      = mlo[i];
    zp[zbase + 64 + lane] = mhi[i];
    sp[zbase + lane]      = mlo[i];
    sp[zbase + 64 + lane] = mhi[i];

    const size_t pbase = (size_t)r[i] * 384 + 3u * (uint32_t)lane;
    F3 a = { ox + dx * mlo[i], oy + dy * mlo[i], oz + dz * mlo[i] };
    F3 b = { ox + dx * mhi[i], oy + dy * mhi[i], oz + dz * mhi[i] };
    *(F3*)(pts + pbase)       = a;
    *(F3*)(pts + pbase + 192) = b;
  }
}

extern "C" void kernel_launch(void* const* d_in, const int* in_sizes, int n_in,
                              void* d_out, int out_size, void* d_ws, size_t ws_size,
                              hipStream_t stream) {
  const float* rays_o  = (const float*)d_in[0];
  const float* rays_d  = (const float*)d_in[1];
  const float* s_vals  = (const float*)d_in[2];
  const float* weights = (const float*)d_in[3];
  float* out = (float*)d_out;

  const int nrays = in_sizes[2] / 64;      // 131072
  const int blocks = (nrays + 7) / 8;      // 4 waves/block x 2 rays/wave

  newsampler_kernel<<<blocks, 256, 0, stream>>>(rays_o, rays_d, s_vals, weights,
                                                out, nrays);
}